// Round 1
// baseline (3405.919 us; speedup 1.0000x reference)
//
#include <hip/hip_runtime.h>
#include <math.h>

// MambaNet forward: stem (conv/BN/relu) -> 6x [LN -> Mamba -> LN -> MLP] -> pool -> fc
// All f32. T = 18432 tokens (B=2, L=9216), d_model=64, d_inner=128, N_state=16.

#define TTOK 18432
#define LSEQ 9216
#define BSZ 2
#define CS 96     // scan chunk size
#define NCH 96    // number of chunks (CS*NCH == LSEQ)

__device__ __forceinline__ float sigmoidf_(float x){ return 1.f/(1.f+expf(-x)); }

// ---------------- Stem ----------------
__global__ __launch_bounds__(256) void k_stem_conv1(const float* __restrict__ x,
    const float* __restrict__ w1, const float* __restrict__ scw,
    float* __restrict__ c1, float* __restrict__ res){
  int idx = blockIdx.x*256 + threadIdx.x;
  if (idx >= BSZ*64*9216) return;
  int hw = idx % 9216; int c = (idx/9216) & 63; int b = idx/(9216*64);
  int h = hw/96, w = hw%96;
  const float* xb = x + b*9216;
  float acc = 0.f;
  for (int dh=-1; dh<=1; ++dh){
    int hh=h+dh; if(hh<0||hh>=96) continue;
    for (int dw=-1; dw<=1; ++dw){
      int ww=w+dw; if(ww<0||ww>=96) continue;
      acc += xb[hh*96+ww]*w1[c*9+(dh+1)*3+(dw+1)];
    }
  }
  c1[idx]=acc;
  res[idx]=xb[hw]*scw[c];
}

// per-channel batch stats over (B, HW) for NCHW tensor, C=64
__global__ __launch_bounds__(256) void k_bnstats(const float* __restrict__ src,
    float* __restrict__ mean, float* __restrict__ istd){
  int c = blockIdx.x; int tid = threadIdx.x;
  float s=0.f, s2=0.f;
  for (int b=0;b<BSZ;++b){
    const float* p = src + (size_t)(b*64+c)*9216;
    for (int i=tid;i<9216;i+=256){ float v=p[i]; s+=v; s2+=v*v; }
  }
  __shared__ float ls[256], ls2[256];
  ls[tid]=s; ls2[tid]=s2; __syncthreads();
  for(int off=128;off>0;off>>=1){
    if(tid<off){ ls[tid]+=ls[tid+off]; ls2[tid]+=ls2[tid+off]; }
    __syncthreads();
  }
  if(tid==0){
    float m=ls[0]/18432.f; float v=ls2[0]/18432.f - m*m;
    mean[c]=m; istd[c]=rsqrtf(v+1e-5f);
  }
}

__global__ __launch_bounds__(256) void k_bnrelu(float* __restrict__ t,
    const float* __restrict__ mean, const float* __restrict__ istd,
    const float* __restrict__ g, const float* __restrict__ bb){
  int idx = blockIdx.x*256+threadIdx.x; if(idx>=BSZ*64*9216) return;
  int c=(idx/9216)&63;
  float v=(t[idx]-mean[c])*istd[c]*g[c]+bb[c];
  t[idx]=fmaxf(v,0.f);
}

__global__ __launch_bounds__(256) void k_stem_conv2(const float* __restrict__ h1,
    const float* __restrict__ w2, float* __restrict__ c2){
  int idx=blockIdx.x*256+threadIdx.x; if(idx>=BSZ*64*9216)return;
  int hw=idx%9216; int c=(idx/9216)&63; int b=idx/(9216*64);
  int h=hw/96, w=hw%96;
  float acc=0.f;
  const float* wc = w2 + c*64*9;
  const float* hb = h1 + (size_t)b*64*9216;
  for(int ci=0;ci<64;++ci){
    const float* hc = hb + ci*9216;
    const float* wk = wc + ci*9;
    #pragma unroll
    for(int dh=-1;dh<=1;++dh){
      int hh=h+dh; if(hh<0||hh>=96) continue;
      #pragma unroll
      for(int dw=-1;dw<=1;++dw){
        int ww=w+dw; if(ww<0||ww>=96) continue;
        acc += hc[hh*96+ww]*wk[(dh+1)*3+(dw+1)];
      }
    }
  }
  c2[idx]=acc;
}

// merge: h[b,hw,c] = relu(bn2(c2) + bn_sc(res))  (NCHW -> token-major channel-last)
__global__ __launch_bounds__(256) void k_stem_merge(const float* __restrict__ c2,
    const float* __restrict__ res,
    const float* __restrict__ m2,const float* __restrict__ i2,
    const float* __restrict__ g2,const float* __restrict__ b2,
    const float* __restrict__ ms,const float* __restrict__ is,
    const float* __restrict__ gs,const float* __restrict__ bs,
    float* __restrict__ hOut){
  int idx=blockIdx.x*256+threadIdx.x; if(idx>=BSZ*64*9216)return;
  int c=idx&63; int hw=(idx>>6)%9216; int b=idx/(64*9216);
  size_t src=(size_t)(b*64+c)*9216+hw;
  float v=(c2[src]-m2[c])*i2[c]*g2[c]+b2[c];
  float r=(res[src]-ms[c])*is[c]*gs[c]+bs[c];
  hOut[idx]=fmaxf(v+r,0.f);
}

// ---------------- LayerNorm over 64 channels (1 token per wave) ----------------
__global__ __launch_bounds__(256) void k_ln(const float* __restrict__ h,
    const float* __restrict__ g, const float* __restrict__ bb, float* __restrict__ out){
  int t = blockIdx.x*4 + (threadIdx.x>>6);
  int c = threadIdx.x & 63;
  if (t >= TTOK) return;
  float v = h[(size_t)t*64+c];
  float s=v, s2=v*v;
  #pragma unroll
  for(int off=32;off>0;off>>=1){ s += __shfl_xor(s,off); s2 += __shfl_xor(s2,off); }
  float m = s*(1.f/64.f);
  float var = s2*(1.f/64.f) - m*m;
  float rstd = rsqrtf(var+1e-5f);
  out[(size_t)t*64+c] = (v-m)*rstd*g[c]+bb[c];
}

// ---------------- Generic small GEMM: out(T,N) = A(T,K) @ W(N,K)^T ----------------
// op: 0 = plain (+bias), 1 = gelu(acc+bias), 2 = residual add (+bias)
template<int TB, int LDSZ>
__global__ __launch_bounds__(256) void k_gemm(
    const float* __restrict__ A, const float* __restrict__ W,
    const float* __restrict__ bias, const float* __restrict__ res,
    float* __restrict__ out, int T, int N, int K, int tokensPerBlock, int op){
  __shared__ __align__(16) float lds[LDSZ];
  float* Wl = lds;               // [K][N] transposed
  int G = 256/N;
  float* Al = lds + N*K;         // [G*TB][K]
  int tid = threadIdx.x;
  for (int i=tid;i<N*K;i+=256){ int j=i/K, k=i%K; Wl[k*N+j]=W[i]; }
  int j = tid % N; int tg = tid / N;
  bool active = tg < G;
  int tStart = blockIdx.x*tokensPerBlock;
  int tEnd = min(tStart+tokensPerBlock, T);
  int tokPerIter = G*TB;
  for (int t0=tStart; t0<tEnd; t0+=tokPerIter){
    __syncthreads();
    for (int i=tid;i<tokPerIter*K;i+=256){
      int r=i/K, kk=i%K; int t=t0+r;
      Al[i] = (t<tEnd)? A[(size_t)t*K+kk] : 0.f;
    }
    __syncthreads();
    if (active){
      float acc[TB];
      #pragma unroll
      for(int i=0;i<TB;++i) acc[i] = bias? bias[j] : 0.f;
      const float* ar = Al + tg*TB*K;
      for (int k=0;k<K;k+=4){
        float w0=Wl[k*N+j], w1=Wl[(k+1)*N+j], w2=Wl[(k+2)*N+j], w3=Wl[(k+3)*N+j];
        #pragma unroll
        for(int i=0;i<TB;++i){
          float4 a = *reinterpret_cast<const float4*>(ar + i*K + k);
          acc[i] += a.x*w0 + a.y*w1 + a.z*w2 + a.w*w3;
        }
      }
      #pragma unroll
      for(int i=0;i<TB;++i){
        int t = t0 + tg*TB + i;
        if (t < tEnd){
          float v = acc[i];
          if (op==1)      v = 0.5f*v*(1.f+erff(v*0.70710678118f));
          else if (op==2) v += res[(size_t)t*N+j];
          out[(size_t)t*N+j] = v;
        }
      }
    }
  }
}

// ---------------- depthwise causal conv (k=4) + silu ----------------
__global__ __launch_bounds__(256) void k_dwconv(const float* __restrict__ xz,
    const float* __restrict__ cw, const float* __restrict__ cb, float* __restrict__ xc){
  int idx=blockIdx.x*256+threadIdx.x; if(idx>=TTOK*128)return;
  int d=idx&127; int t=idx>>7;
  int b=t/LSEQ, l=t%LSEQ;
  float acc=cb[d];
  #pragma unroll
  for(int k=0;k<4;++k){
    int ls=l-3+k;
    if(ls>=0) acc += cw[d*4+k]*xz[(size_t)(b*LSEQ+ls)*256 + d];
  }
  xc[idx]=acc*sigmoidf_(acc);
}

// ---------------- delta = softplus(dt @ dtw^T + dtb) ----------------
__global__ __launch_bounds__(256) void k_delta(const float* __restrict__ dbl,
    const float* __restrict__ dtw, const float* __restrict__ dtb, float* __restrict__ delta){
  int idx=blockIdx.x*256+threadIdx.x; if(idx>=TTOK*128) return;
  int d=idx&127; int t=idx>>7;
  const float* dt = dbl + (size_t)t*36;
  float acc = dtb[d];
  #pragma unroll
  for(int r=0;r<4;++r) acc += dt[r]*dtw[d*4+r];
  delta[idx] = fmaxf(acc,0.f) + log1pf(expf(-fabsf(acc)));   // stable softplus
}

// ---------------- scan phase 1: per-chunk (prod a, local end-state) ----------------
__global__ __launch_bounds__(256) void k_scan1(const float* __restrict__ delta,
    const float* __restrict__ xc, const float* __restrict__ dbl,
    const float* __restrict__ A_log, float* __restrict__ chA, float* __restrict__ chH){
  int idx=blockIdx.x*256+threadIdx.x;   // B*NCH*2048
  int n=idx&15; int d=(idx>>4)&127; int chunk=(idx>>11)%NCH; int b=(idx>>11)/NCH;
  float a_const = -expf(A_log[d*16+n]);
  float aprod=1.f, h=0.f;
  int tBase = b*LSEQ + chunk*CS;
  for(int i=0;i<CS;++i){
    int t=tBase+i;
    float dl=delta[(size_t)t*128+d];
    float xv=xc[(size_t)t*128+d];
    float Bv=dbl[(size_t)t*36+4+n];
    float da=expf(dl*a_const);
    h = da*h + dl*xv*Bv;
    aprod *= da;
  }
  chA[idx]=aprod; chH[idx]=h;
}

// ---------------- scan phase 2: cross-chunk boundary states ----------------
__global__ __launch_bounds__(256) void k_scan2(const float* __restrict__ chA,
    const float* __restrict__ chH, float* __restrict__ chIn){
  int idx=blockIdx.x*256+threadIdx.x; if(idx>=BSZ*2048) return;
  int b=idx>>11; int dn=idx&2047;
  float H=0.f;
  for(int c=0;c<NCH;++c){
    size_t o=(size_t)(b*NCH+c)*2048+dn;
    chIn[o]=H;
    H = chA[o]*H + chH[o];
  }
}

// ---------------- scan phase 3: recompute with boundary state, emit y ----------------
__global__ __launch_bounds__(256) void k_scan3(const float* __restrict__ delta,
    const float* __restrict__ xc, const float* __restrict__ dbl,
    const float* __restrict__ A_log, const float* __restrict__ chIn, float* __restrict__ y){
  int tid=threadIdx.x;
  int gid = blockIdx.x*16 + (tid>>4);  // over B*NCH*128 groups of 16 lanes
  int n = tid&15;
  int d = gid%128; int chunk=(gid/128)%NCH; int b=gid/(128*NCH);
  float a_const = -expf(A_log[d*16+n]);
  float h = chIn[(size_t)(b*NCH+chunk)*2048 + d*16+n];
  int tBase=b*LSEQ+chunk*CS;
  for(int i=0;i<CS;++i){
    int t=tBase+i;
    float dl=delta[(size_t)t*128+d];
    float xv=xc[(size_t)t*128+d];
    float Bv=dbl[(size_t)t*36+4+n];
    float Cv=dbl[(size_t)t*36+20+n];
    float da=expf(dl*a_const);
    h=da*h+dl*xv*Bv;
    float contrib=h*Cv;
    contrib += __shfl_xor(contrib,1);
    contrib += __shfl_xor(contrib,2);
    contrib += __shfl_xor(contrib,4);
    contrib += __shfl_xor(contrib,8);
    if(n==0) y[(size_t)t*128+d]=contrib;
  }
}

// ---------------- gate: y = (y + xc*D) * silu(z) ----------------
__global__ __launch_bounds__(256) void k_gate(const float* __restrict__ xz,
    const float* __restrict__ xc, const float* __restrict__ Dp, float* __restrict__ y){
  int idx=blockIdx.x*256+threadIdx.x; if(idx>=TTOK*128)return;
  int d=idx&127; int t=idx>>7;
  float z=xz[(size_t)t*256+128+d];
  y[idx]=(y[idx] + xc[idx]*Dp[d]) * (z*sigmoidf_(z));
}

// ---------------- global mean pool + fc ----------------
__global__ __launch_bounds__(256) void k_pool_fc(const float* __restrict__ h,
    const float* __restrict__ fcw, const float* __restrict__ fcb, float* __restrict__ out){
  int b=blockIdx.x; int tid=threadIdx.x;
  int c=tid&63, sl=tid>>6;
  float s=0.f;
  for (int hw=sl; hw<9216; hw+=4) s += h[((size_t)b*9216+hw)*64 + c];
  __shared__ float ls[256];
  ls[tid]=s; __syncthreads();
  if(sl==0){
    float tot = ls[c]+ls[64+c]+ls[128+c]+ls[192+c];
    float v = (tot/9216.f)*fcw[c];
    #pragma unroll
    for(int off=32;off>0;off>>=1) v += __shfl_xor(v,off);
    if(c==0) out[b]=v+fcb[0];
  }
}

// ---------------- host ----------------
static inline void gemm_launch(const float* A, const float* W, const float* bias,
    const float* res, float* out, int T, int N, int K, int op, hipStream_t s){
  int G = 256/N;
  if (K==256){
    int tpb = G*4*2; int grid=(T+tpb-1)/tpb;
    k_gemm<4,20480><<<grid,256,0,s>>>(A,W,bias,res,out,T,N,K,tpb,op);
  } else {
    int tpb = G*8*2; int grid=(T+tpb-1)/tpb;
    k_gemm<8,16896><<<grid,256,0,s>>>(A,W,bias,res,out,T,N,K,tpb,op);
  }
}

extern "C" void kernel_launch(void* const* d_in, const int* in_sizes, int n_in,
                              void* d_out, int out_size, void* d_ws, size_t ws_size,
                              hipStream_t stream) {
  const float* x       = (const float*)d_in[0];
  const float* conv1_w = (const float*)d_in[1];
  const float* bn1_g   = (const float*)d_in[2];
  const float* bn1_b   = (const float*)d_in[3];
  const float* conv2_w = (const float*)d_in[4];
  const float* bn2_g   = (const float*)d_in[5];
  const float* bn2_b   = (const float*)d_in[6];
  const float* sc_w    = (const float*)d_in[7];
  const float* sc_g    = (const float*)d_in[8];
  const float* sc_b    = (const float*)d_in[9];
  const float* ln1_g   = (const float*)d_in[10];
  const float* ln1_b   = (const float*)d_in[11];
  const float* in_proj_w = (const float*)d_in[12];
  const float* conv_w  = (const float*)d_in[13];
  const float* conv_b  = (const float*)d_in[14];
  const float* x_proj_w= (const float*)d_in[15];
  const float* dt_w    = (const float*)d_in[16];
  const float* dt_b    = (const float*)d_in[17];
  const float* A_log   = (const float*)d_in[18];
  const float* Dp      = (const float*)d_in[19];
  const float* out_proj_w = (const float*)d_in[20];
  const float* ln2_g   = (const float*)d_in[21];
  const float* ln2_b   = (const float*)d_in[22];
  const float* mlp_w1  = (const float*)d_in[23];
  const float* mlp_b1  = (const float*)d_in[24];
  const float* mlp_w2  = (const float*)d_in[25];
  const float* mlp_b2  = (const float*)d_in[26];
  const float* fc_w    = (const float*)d_in[27];
  const float* fc_b    = (const float*)d_in[28];

  const size_t T = TTOK;
  float* ws   = (float*)d_ws;
  float* bufH  = ws;                  // T*64
  float* bufHN = bufH  + 64*T;        // T*64
  float* bufXZ = bufHN + 64*T;        // T*256 (also MLP hidden, stem scratch)
  float* bufXC = bufXZ + 256*T;       // T*128
  float* bufDBL= bufXC + 128*T;       // T*36
  float* bufDLT= bufDBL+ 36*T;        // T*128
  float* bufY  = bufDLT+ 128*T;       // T*128
  float* chA   = bufY  + 128*T;       // B*NCH*2048
  float* chH   = chA   + BSZ*NCH*2048;
  float* chIn  = chH   + BSZ*NCH*2048;
  float* stats = chIn  + BSZ*NCH*2048; // 6*64

  // stem scratch aliases inside bufXZ (each 2*64*9216 = 1179648 floats)
  float* c1   = bufXZ;
  float* c2   = bufXZ + 1179648;
  float* resb = bufXZ + 2*1179648;
  float *m1=stats, *i1=stats+64, *m2=stats+128, *i2=stats+192, *ms=stats+256, *is=stats+320;

  const int NE = BSZ*64*9216;
  const int gE = (NE+255)/256;

  k_stem_conv1<<<gE,256,0,stream>>>(x, conv1_w, sc_w, c1, resb);
  k_bnstats<<<64,256,0,stream>>>(c1, m1, i1);
  k_bnstats<<<64,256,0,stream>>>(resb, ms, is);
  k_bnrelu<<<gE,256,0,stream>>>(c1, m1, i1, bn1_g, bn1_b);
  k_stem_conv2<<<gE,256,0,stream>>>(c1, conv2_w, c2);
  k_bnstats<<<64,256,0,stream>>>(c2, m2, i2);
  k_stem_merge<<<gE,256,0,stream>>>(c2, resb, m2, i2, bn2_g, bn2_b, ms, is, sc_g, sc_b, bufH);

  const int gD = (int)((T*128+255)/256);
  for (int i=0;i<6;++i){
    const float* inw  = in_proj_w + (size_t)i*256*64;
    const float* cw   = conv_w    + (size_t)i*128*4;
    const float* cb   = conv_b    + (size_t)i*128;
    const float* xpw  = x_proj_w  + (size_t)i*36*128;
    const float* dtw  = dt_w      + (size_t)i*128*4;
    const float* dtb  = dt_b      + (size_t)i*128;
    const float* alog = A_log     + (size_t)i*128*16;
    const float* dp   = Dp        + (size_t)i*128;
    const float* opw  = out_proj_w+ (size_t)i*64*128;
    const float* w1   = mlp_w1    + (size_t)i*256*64;
    const float* b1   = mlp_b1    + (size_t)i*256;
    const float* w2   = mlp_w2    + (size_t)i*64*256;
    const float* b2   = mlp_b2    + (size_t)i*64;

    k_ln<<<TTOK/4,256,0,stream>>>(bufH, ln1_g+i*64, ln1_b+i*64, bufHN);
    gemm_launch(bufHN, inw, nullptr, nullptr, bufXZ, TTOK, 256, 64, 0, stream);
    k_dwconv<<<gD,256,0,stream>>>(bufXZ, cw, cb, bufXC);
    gemm_launch(bufXC, xpw, nullptr, nullptr, bufDBL, TTOK, 36, 128, 0, stream);
    k_delta<<<gD,256,0,stream>>>(bufDBL, dtw, dtb, bufDLT);
    k_scan1<<<BSZ*NCH*2048/256,256,0,stream>>>(bufDLT, bufXC, bufDBL, alog, chA, chH);
    k_scan2<<<(BSZ*2048+255)/256,256,0,stream>>>(chA, chH, chIn);
    k_scan3<<<BSZ*NCH*128/16,256,0,stream>>>(bufDLT, bufXC, bufDBL, alog, chIn, bufY);
    k_gate<<<gD,256,0,stream>>>(bufXZ, bufXC, dp, bufY);
    gemm_launch(bufY, opw, nullptr, bufH, bufH, TTOK, 64, 128, 2, stream);
    k_ln<<<TTOK/4,256,0,stream>>>(bufH, ln2_g+i*64, ln2_b+i*64, bufHN);
    gemm_launch(bufHN, w1, b1, nullptr, bufXZ, TTOK, 256, 64, 1, stream);
    gemm_launch(bufXZ, w2, b2, bufH, bufH, TTOK, 64, 256, 2, stream);
  }

  k_pool_fc<<<BSZ,256,0,stream>>>(bufH, fc_w, fc_b, (float*)d_out);
}

// Round 3
// 3204.583 us; speedup vs baseline: 1.0628x; 1.0628x over previous
//
#include <hip/hip_runtime.h>
#include <math.h>

// MambaNet forward: stem (conv/BN/relu) -> 6x [LN -> Mamba -> LN -> MLP] -> pool -> fc
// All f32. T = 18432 tokens (B=2, L=9216), d_model=64, d_inner=128, N_state=16.

#define TTOK 18432
#define LSEQ 9216
#define BSZ 2
#define CS 96     // scan chunk size
#define NCH 96    // number of chunks (CS*NCH == LSEQ)

__device__ __forceinline__ float sigmoidf_(float x){ return 1.f/(1.f+expf(-x)); }

// ---------------- Stem ----------------
__global__ __launch_bounds__(256) void k_stem_conv1(const float* __restrict__ x,
    const float* __restrict__ w1, const float* __restrict__ scw,
    float* __restrict__ c1, float* __restrict__ res){
  int idx = blockIdx.x*256 + threadIdx.x;
  if (idx >= BSZ*64*9216) return;
  int hw = idx % 9216; int c = (idx/9216) & 63; int b = idx/(9216*64);
  int h = hw/96, w = hw%96;
  const float* xb = x + b*9216;
  float acc = 0.f;
  for (int dh=-1; dh<=1; ++dh){
    int hh=h+dh; if(hh<0||hh>=96) continue;
    for (int dw=-1; dw<=1; ++dw){
      int ww=w+dw; if(ww<0||ww>=96) continue;
      acc += xb[hh*96+ww]*w1[c*9+(dh+1)*3+(dw+1)];
    }
  }
  c1[idx]=acc;
  res[idx]=xb[hw]*scw[c];
}

// per-channel batch stats for TWO tensors in one launch (128 blocks)
__global__ __launch_bounds__(256) void k_bnstats2(const float* __restrict__ srcA,
    const float* __restrict__ srcB,
    float* __restrict__ meanA, float* __restrict__ istdA,
    float* __restrict__ meanB, float* __restrict__ istdB){
  int c = blockIdx.x & 63; int tid = threadIdx.x;
  const float* src = (blockIdx.x < 64)? srcA : srcB;
  float* mean = (blockIdx.x < 64)? meanA : meanB;
  float* istd = (blockIdx.x < 64)? istdA : istdB;
  float s=0.f, s2=0.f;
  for (int b=0;b<BSZ;++b){
    const float* p = src + (size_t)(b*64+c)*9216;
    for (int i=tid;i<9216;i+=256){ float v=p[i]; s+=v; s2+=v*v; }
  }
  __shared__ float ls[256], ls2[256];
  ls[tid]=s; ls2[tid]=s2; __syncthreads();
  for(int off=128;off>0;off>>=1){
    if(tid<off){ ls[tid]+=ls[tid+off]; ls2[tid]+=ls2[tid+off]; }
    __syncthreads();
  }
  if(tid==0){
    float m=ls[0]/18432.f; float v=ls2[0]/18432.f - m*m;
    mean[c]=m; istd[c]=rsqrtf(v+1e-5f);
  }
}

__global__ __launch_bounds__(256) void k_bnstats(const float* __restrict__ src,
    float* __restrict__ mean, float* __restrict__ istd){
  int c = blockIdx.x; int tid = threadIdx.x;
  float s=0.f, s2=0.f;
  for (int b=0;b<BSZ;++b){
    const float* p = src + (size_t)(b*64+c)*9216;
    for (int i=tid;i<9216;i+=256){ float v=p[i]; s+=v; s2+=v*v; }
  }
  __shared__ float ls[256], ls2[256];
  ls[tid]=s; ls2[tid]=s2; __syncthreads();
  for(int off=128;off>0;off>>=1){
    if(tid<off){ ls[tid]+=ls[tid+off]; ls2[tid]+=ls2[tid+off]; }
    __syncthreads();
  }
  if(tid==0){
    float m=ls[0]/18432.f; float v=ls2[0]/18432.f - m*m;
    mean[c]=m; istd[c]=rsqrtf(v+1e-5f);
  }
}

__global__ __launch_bounds__(256) void k_bnrelu(float* __restrict__ t,
    const float* __restrict__ mean, const float* __restrict__ istd,
    const float* __restrict__ g, const float* __restrict__ bb){
  int idx = blockIdx.x*256+threadIdx.x; if(idx>=BSZ*64*9216) return;
  int c=(idx/9216)&63;
  float v=(t[idx]-mean[c])*istd[c]*g[c]+bb[c];
  t[idx]=fmaxf(v,0.f);
}

// Tiled direct conv 64->64, 3x3. Block = (b, out-row h, half-row wh).
// Thread: co = tid&63, pg = tid>>6 owns 12 consecutive output pixels.
// Input strip + weight chunk staged in LDS; window reads are wave-broadcast.
__global__ __launch_bounds__(256) void k_stem_conv2(const float* __restrict__ h1,
    const float* __restrict__ w2, float* __restrict__ c2){
  __shared__ __align__(16) float in_lds[16*156];   // [ci][3][52]
  __shared__ float w_lds[64*145];                  // [co][16*9 (+1 pad)]
  int blk=blockIdx.x;
  int wh=blk&1, h=(blk>>1)%96, b=blk/(2*96);
  int tid=threadIdx.x;
  int co=tid&63, pg=tid>>6;
  float acc[12];
  #pragma unroll
  for(int i=0;i<12;++i) acc[i]=0.f;
  int wbase = wh*48;
  const float* hb = h1 + (size_t)b*64*9216;
  for(int cc=0;cc<4;++cc){
    __syncthreads();
    for(int e=tid;e<16*3*50;e+=256){
      int ci=e/150, rr=e%150; int tr=rr/50, wl=rr%50;
      int hh=h+tr-1, ww=wbase+wl-1;
      float v=0.f;
      if(hh>=0&&hh<96&&ww>=0&&ww<96) v=hb[(size_t)(cc*16+ci)*9216 + hh*96+ww];
      in_lds[ci*156 + tr*52 + wl]=v;
    }
    for(int e=tid;e<64*144;e+=256){
      int c_=e/144, r=e%144;
      w_lds[c_*145+r]=w2[(size_t)c_*576 + cc*144 + r];
    }
    __syncthreads();
    for(int ci=0;ci<16;++ci){
      float wr[9];
      #pragma unroll
      for(int t=0;t<9;++t) wr[t]=w_lds[co*145+ci*9+t];
      const float* ibase = in_lds + ci*156;
      #pragma unroll
      for(int tr=0;tr<3;++tr){
        const float* row = ibase + tr*52 + pg*12;
        float win[14];
        #pragma unroll
        for(int q=0;q<14;++q) win[q]=row[q];
        #pragma unroll
        for(int p=0;p<12;++p)
          acc[p] += win[p]*wr[tr*3+0] + win[p+1]*wr[tr*3+1] + win[p+2]*wr[tr*3+2];
      }
    }
  }
  size_t obase=(size_t)(b*64+co)*9216 + h*96 + wbase + pg*12;
  #pragma unroll
  for(int p=0;p<3;++p)
    *reinterpret_cast<float4*>(&c2[obase+p*4]) = *reinterpret_cast<float4*>(&acc[p*4]);
}

// merge: h[b,hw,c] = relu(bn2(c2) + bn_sc(res))  (NCHW -> token-major channel-last)
__global__ __launch_bounds__(256) void k_stem_merge(const float* __restrict__ c2,
    const float* __restrict__ res,
    const float* __restrict__ m2,const float* __restrict__ i2,
    const float* __restrict__ g2,const float* __restrict__ b2,
    const float* __restrict__ ms,const float* __restrict__ is,
    const float* __restrict__ gs,const float* __restrict__ bs,
    float* __restrict__ hOut){
  int idx=blockIdx.x*256+threadIdx.x; if(idx>=BSZ*64*9216)return;
  int c=idx&63; int hw=(idx>>6)%9216; int b=idx/(64*9216);
  size_t src=(size_t)(b*64+c)*9216+hw;
  float v=(c2[src]-m2[c])*i2[c]*g2[c]+b2[c];
  float r=(res[src]-ms[c])*is[c]*gs[c]+bs[c];
  hOut[idx]=fmaxf(v+r,0.f);
}

// ---------------- fused LayerNorm + GEMM (N=256, K=64) ----------------
// out(T,256) = LN(A)(T,64) @ W(256,64)^T ; OP==1 -> gelu(acc+bias)
template<int OP>
__global__ __launch_bounds__(256) void k_ln_gemm(
    const float* __restrict__ A, const float* __restrict__ lng, const float* __restrict__ lnb,
    const float* __restrict__ W, const float* __restrict__ bias,
    float* __restrict__ out, int tokensPerBlock){
  __shared__ __align__(16) float lds[256*64 + 8*64];
  float* Wl = lds;             // [64][256]
  float* Al = lds + 256*64;    // [8][64]
  int tid = threadIdx.x;
  for (int i=tid;i<256*64;i+=256){ int j=i>>6, k=i&63; Wl[k*256+j]=W[i]; }
  float gg = lng[tid&63], bbv = lnb[tid&63];
  int j = tid;
  int tStart = blockIdx.x*tokensPerBlock;
  for (int t0=tStart; t0<tStart+tokensPerBlock; t0+=8){
    __syncthreads();
    #pragma unroll
    for (int p=0;p<2;++p){
      int r = p*4 + (tid>>6);
      int c = tid&63;
      int t = t0 + r;
      float v = (t<TTOK)? A[(size_t)t*64+c] : 0.f;
      float s=v, s2=v*v;
      #pragma unroll
      for(int off=32;off>0;off>>=1){ s+=__shfl_xor(s,off); s2+=__shfl_xor(s2,off); }
      float m=s*(1.f/64.f), var=s2*(1.f/64.f)-m*m;
      Al[r*64+c] = (v-m)*rsqrtf(var+1e-5f)*gg + bbv;
    }
    __syncthreads();
    float acc[8];
    #pragma unroll
    for(int i=0;i<8;++i) acc[i] = (OP==1)? bias[j] : 0.f;
    for (int k=0;k<64;k+=4){
      float w0=Wl[k*256+j],w1=Wl[(k+1)*256+j],w2=Wl[(k+2)*256+j],w3=Wl[(k+3)*256+j];
      #pragma unroll
      for(int i=0;i<8;++i){
        float4 a=*reinterpret_cast<const float4*>(Al+i*64+k);
        acc[i]+=a.x*w0+a.y*w1+a.z*w2+a.w*w3;
      }
    }
    #pragma unroll
    for(int i=0;i<8;++i){
      int t=t0+i;
      if(t<TTOK){
        float v=acc[i];
        if(OP==1) v=0.5f*v*(1.f+erff(v*0.70710678118f));
        out[(size_t)t*256+j]=v;
      }
    }
  }
}

// ---------------- Generic small GEMM: out(T,N) = A(T,K) @ W(N,K)^T ----------------
// op: 0 = plain (+bias), 2 = residual add (+bias)
template<int TB, int LDSZ>
__global__ __launch_bounds__(256) void k_gemm(
    const float* __restrict__ A, const float* __restrict__ W,
    const float* __restrict__ bias, const float* __restrict__ res,
    float* __restrict__ out, int T, int N, int K, int tokensPerBlock, int op){
  __shared__ __align__(16) float lds[LDSZ];
  float* Wl = lds;               // [K][N]
  int G = 256/N;
  float* Al = lds + N*K;         // [G*TB][K]
  int tid = threadIdx.x;
  for (int i=tid;i<N*K;i+=256){ int j=i/K, k=i%K; Wl[k*N+j]=W[i]; }
  int j = tid % N; int tg = tid / N;
  bool active = tg < G;
  int tStart = blockIdx.x*tokensPerBlock;
  int tEnd = min(tStart+tokensPerBlock, T);
  int tokPerIter = G*TB;
  for (int t0=tStart; t0<tEnd; t0+=tokPerIter){
    __syncthreads();
    for (int i=tid;i<tokPerIter*K;i+=256){
      int r=i/K, kk=i%K; int t=t0+r;
      Al[i] = (t<tEnd)? A[(size_t)t*K+kk] : 0.f;
    }
    __syncthreads();
    if (active){
      float acc[TB];
      #pragma unroll
      for(int i=0;i<TB;++i) acc[i] = bias? bias[j] : 0.f;
      const float* ar = Al + tg*TB*K;
      for (int k=0;k<K;k+=4){
        float w0=Wl[k*N+j], w1=Wl[(k+1)*N+j], w2=Wl[(k+2)*N+j], w3=Wl[(k+3)*N+j];
        #pragma unroll
        for(int i=0;i<TB;++i){
          float4 a = *reinterpret_cast<const float4*>(ar + i*K + k);
          acc[i] += a.x*w0 + a.y*w1 + a.z*w2 + a.w*w3;
        }
      }
      #pragma unroll
      for(int i=0;i<TB;++i){
        int t = t0 + tg*TB + i;
        if (t < tEnd){
          float v = acc[i];
          if (op==2) v += res[(size_t)t*N+j];
          out[(size_t)t*N+j] = v;
        }
      }
    }
  }
}

// ---------------- depthwise causal conv (k=4) + silu ----------------
__global__ __launch_bounds__(256) void k_dwconv(const float* __restrict__ xz,
    const float* __restrict__ cw, const float* __restrict__ cb, float* __restrict__ xc){
  int idx=blockIdx.x*256+threadIdx.x; if(idx>=TTOK*128)return;
  int d=idx&127; int t=idx>>7;
  int b=t/LSEQ, l=t%LSEQ;
  float acc=cb[d];
  #pragma unroll
  for(int k=0;k<4;++k){
    int ls=l-3+k;
    if(ls>=0) acc += cw[d*4+k]*xz[(size_t)(b*LSEQ+ls)*256 + d];
  }
  xc[idx]=acc*sigmoidf_(acc);
}

// ---------------- x_proj GEMM (N=36,K=128) + fused delta ----------------
__global__ __launch_bounds__(256) void k_xproj_delta(
    const float* __restrict__ A, const float* __restrict__ W,
    const float* __restrict__ dtw, const float* __restrict__ dtb,
    float* __restrict__ dbl, float* __restrict__ delta, int tokensPerBlock){
  __shared__ __align__(16) float lds[36*128 + 56*128 + 56*4 + 512 + 128];
  float* Wl  = lds;               // [128][36]
  float* Al  = Wl + 36*128;       // [56][128]
  float* dtv = Al + 56*128;       // [56][4]
  float* dtwl= dtv + 56*4;        // [128][4]
  float* dtbl= dtwl + 512;        // [128]
  int tid=threadIdx.x;
  for(int i=tid;i<36*128;i+=256){int jj=i/128,kk=i%128; Wl[kk*36+jj]=W[i];}
  for(int i=tid;i<512;i+=256) dtwl[i]=dtw[i];
  if(tid<128) dtbl[tid]=dtb[tid];
  int j=tid%36, tg=tid/36;
  bool active = tg<7;
  int tStart=blockIdx.x*tokensPerBlock;
  for(int t0=tStart;t0<tStart+tokensPerBlock;t0+=56){
    __syncthreads();
    for(int i=tid;i<56*128;i+=256){
      int r=i>>7, kk=i&127; int t=t0+r;
      Al[i]=(t<TTOK)?A[(size_t)t*128+kk]:0.f;
    }
    __syncthreads();
    if(active){
      float acc[8];
      #pragma unroll
      for(int i=0;i<8;++i) acc[i]=0.f;
      const float* ar=Al+tg*8*128;
      for(int k=0;k<128;k+=4){
        float w0=Wl[k*36+j],w1=Wl[(k+1)*36+j],w2=Wl[(k+2)*36+j],w3=Wl[(k+3)*36+j];
        #pragma unroll
        for(int i=0;i<8;++i){
          float4 a=*reinterpret_cast<const float4*>(ar+i*128+k);
          acc[i]+=a.x*w0+a.y*w1+a.z*w2+a.w*w3;
        }
      }
      #pragma unroll
      for(int i=0;i<8;++i){
        int t=t0+tg*8+i;
        if(t<TTOK){
          dbl[(size_t)t*36+j]=acc[i];
          if(j<4) dtv[(tg*8+i)*4+j]=acc[i];
        }
      }
    }
    __syncthreads();
    for(int e=tid;e<56*128;e+=256){
      int r=e>>7, d=e&127; int t=t0+r;
      if(t<TTOK){
        float a0=dtv[r*4+0]*dtwl[d*4+0]+dtv[r*4+1]*dtwl[d*4+1]
                +dtv[r*4+2]*dtwl[d*4+2]+dtv[r*4+3]*dtwl[d*4+3]+dtbl[d];
        delta[(size_t)t*128+d]=fmaxf(a0,0.f)+log1pf(expf(-fabsf(a0)));
      }
    }
  }
}

// ---------------- scan phase 1 ----------------
__global__ __launch_bounds__(256) void k_scan1(const float* __restrict__ delta,
    const float* __restrict__ xc, const float* __restrict__ dbl,
    const float* __restrict__ A_log, float* __restrict__ chA, float* __restrict__ chH){
  int idx=blockIdx.x*256+threadIdx.x;
  int n=idx&15; int d=(idx>>4)&127; int chunk=(idx>>11)%NCH; int b=(idx>>11)/NCH;
  float a_const = -expf(A_log[d*16+n]);
  float aprod=1.f, h=0.f;
  int tBase = b*LSEQ + chunk*CS;
  for(int i=0;i<CS;++i){
    int t=tBase+i;
    float dl=delta[(size_t)t*128+d];
    float xv=xc[(size_t)t*128+d];
    float Bv=dbl[(size_t)t*36+4+n];
    float da=expf(dl*a_const);
    h = da*h + dl*xv*Bv;
    aprod *= da;
  }
  chA[idx]=aprod; chH[idx]=h;
}

// ---------------- scan phase 2 ----------------
__global__ __launch_bounds__(256) void k_scan2(const float* __restrict__ chA,
    const float* __restrict__ chH, float* __restrict__ chIn){
  int idx=blockIdx.x*256+threadIdx.x; if(idx>=BSZ*2048) return;
  int b=idx>>11; int dn=idx&2047;
  float H=0.f;
  for(int c=0;c<NCH;++c){
    size_t o=(size_t)(b*NCH+c)*2048+dn;
    chIn[o]=H;
    H = chA[o]*H + chH[o];
  }
}

// ---------------- scan phase 3 + fused gate ----------------
__global__ __launch_bounds__(256) void k_scan3(const float* __restrict__ delta,
    const float* __restrict__ xc, const float* __restrict__ dbl,
    const float* __restrict__ A_log, const float* __restrict__ chIn,
    const float* __restrict__ xz, const float* __restrict__ Dp,
    float* __restrict__ y){
  int tid=threadIdx.x;
  int gid = blockIdx.x*16 + (tid>>4);
  int n = tid&15;
  int d = gid%128; int chunk=(gid/128)%NCH; int b=gid/(128*NCH);
  float a_const = -expf(A_log[d*16+n]);
  float dpv = Dp[d];
  float h = chIn[(size_t)(b*NCH+chunk)*2048 + d*16+n];
  int tBase=b*LSEQ+chunk*CS;
  for(int i=0;i<CS;++i){
    int t=tBase+i;
    float dl=delta[(size_t)t*128+d];
    float xv=xc[(size_t)t*128+d];
    float Bv=dbl[(size_t)t*36+4+n];
    float Cv=dbl[(size_t)t*36+20+n];
    float da=expf(dl*a_const);
    h=da*h+dl*xv*Bv;
    float contrib=h*Cv;
    contrib += __shfl_xor(contrib,1);
    contrib += __shfl_xor(contrib,2);
    contrib += __shfl_xor(contrib,4);
    contrib += __shfl_xor(contrib,8);
    if(n==0){
      float z=xz[(size_t)t*256+128+d];
      y[(size_t)t*128+d]=(contrib + xv*dpv)*(z*sigmoidf_(z));
    }
  }
}

// ---------------- pool stage 1: 256 blocks of partials ----------------
__global__ __launch_bounds__(256) void k_pool1(const float* __restrict__ h,
    float* __restrict__ partial){
  int blk=blockIdx.x;            // b = blk>>7, slice s = blk&127 (72 px each)
  int b=blk>>7, s=blk&127;
  int tid=threadIdx.x; int c=tid&63, sl=tid>>6;
  float sum=0.f;
  int base = s*72;
  for(int p=sl;p<72;p+=4) sum += h[((size_t)b*9216 + base+p)*64 + c];
  __shared__ float ls[256];
  ls[tid]=sum; __syncthreads();
  if(sl==0) partial[(size_t)blk*64+c] = ls[c]+ls[64+c]+ls[128+c]+ls[192+c];
}

// ---------------- pool stage 2 + fc ----------------
__global__ __launch_bounds__(128) void k_pool2(const float* __restrict__ partial,
    const float* __restrict__ fcw, const float* __restrict__ fcb, float* __restrict__ out){
  int tid=threadIdx.x; int b=tid>>6, c=tid&63;
  float s=0.f;
  for(int k=0;k<128;++k) s += partial[(size_t)(b*128+k)*64+c];
  float v=(s/9216.f)*fcw[c];
  #pragma unroll
  for(int off=32;off>0;off>>=1) v+=__shfl_xor(v,off);
  if(c==0) out[b]=v+fcb[0];
}

// ---------------- host ----------------
static inline void gemm_launch(const float* A, const float* W, const float* bias,
    const float* res, float* out, int T, int N, int K, int op, hipStream_t s){
  int G = 256/N;
  if (K==256){
    int tpb = G*4*2; int grid=(T+tpb-1)/tpb;
    k_gemm<4,20480><<<grid,256,0,s>>>(A,W,bias,res,out,T,N,K,tpb,op);
  } else {
    int tpb = G*8*2; int grid=(T+tpb-1)/tpb;
    k_gemm<8,12288><<<grid,256,0,s>>>(A,W,bias,res,out,T,N,K,tpb,op);
  }
}

extern "C" void kernel_launch(void* const* d_in, const int* in_sizes, int n_in,
                              void* d_out, int out_size, void* d_ws, size_t ws_size,
                              hipStream_t stream) {
  const float* x       = (const float*)d_in[0];
  const float* conv1_w = (const float*)d_in[1];
  const float* bn1_g   = (const float*)d_in[2];
  const float* bn1_b   = (const float*)d_in[3];
  const float* conv2_w = (const float*)d_in[4];
  const float* bn2_g   = (const float*)d_in[5];
  const float* bn2_b   = (const float*)d_in[6];
  const float* sc_w    = (const float*)d_in[7];
  const float* sc_g    = (const float*)d_in[8];
  const float* sc_b    = (const float*)d_in[9];
  const float* ln1_g   = (const float*)d_in[10];
  const float* ln1_b   = (const float*)d_in[11];
  const float* in_proj_w = (const float*)d_in[12];
  const float* conv_w  = (const float*)d_in[13];
  const float* conv_b  = (const float*)d_in[14];
  const float* x_proj_w= (const float*)d_in[15];
  const float* dt_w    = (const float*)d_in[16];
  const float* dt_b    = (const float*)d_in[17];
  const float* A_log   = (const float*)d_in[18];
  const float* Dp      = (const float*)d_in[19];
  const float* out_proj_w = (const float*)d_in[20];
  const float* ln2_g   = (const float*)d_in[21];
  const float* ln2_b   = (const float*)d_in[22];
  const float* mlp_w1  = (const float*)d_in[23];
  const float* mlp_b1  = (const float*)d_in[24];
  const float* mlp_w2  = (const float*)d_in[25];
  const float* mlp_b2  = (const float*)d_in[26];
  const float* fc_w    = (const float*)d_in[27];
  const float* fc_b    = (const float*)d_in[28];

  const size_t T = TTOK;
  float* ws    = (float*)d_ws;
  float* bufH  = ws;                  // T*64
  float* bufXZ = bufH  + 64*T;        // T*256 (also stem scratch)
  float* bufXC = bufXZ + 256*T;       // T*128
  float* bufDBL= bufXC + 128*T;       // T*36
  float* bufDLT= bufDBL+ 36*T;        // T*128
  float* bufY  = bufDLT+ 128*T;       // T*128
  float* chA   = bufY  + 128*T;       // B*NCH*2048
  float* chH   = chA   + BSZ*NCH*2048;
  float* chIn  = chH   + BSZ*NCH*2048;
  float* stats = chIn  + BSZ*NCH*2048; // 6*64
  float* partial = stats + 6*64;       // 256*64

  // stem scratch aliases inside bufXZ (each 2*64*9216 = 1179648 floats)
  float* c1   = bufXZ;
  float* c2   = bufXZ + 1179648;
  float* resb = bufXZ + 2*1179648;
  float *m1=stats, *i1=stats+64, *m2=stats+128, *i2=stats+192, *ms=stats+256, *is=stats+320;

  const int NE = BSZ*64*9216;
  const int gE = (NE+255)/256;

  k_stem_conv1<<<gE,256,0,stream>>>(x, conv1_w, sc_w, c1, resb);
  k_bnstats2<<<128,256,0,stream>>>(c1, resb, m1, i1, ms, is);
  k_bnrelu<<<gE,256,0,stream>>>(c1, m1, i1, bn1_g, bn1_b);
  k_stem_conv2<<<BSZ*96*2,256,0,stream>>>(c1, conv2_w, c2);
  k_bnstats<<<64,256,0,stream>>>(c2, m2, i2);
  k_stem_merge<<<gE,256,0,stream>>>(c2, resb, m2, i2, bn2_g, bn2_b, ms, is, sc_g, sc_b, bufH);

  const int gD = (int)((T*128+255)/256);
  for (int i=0;i<6;++i){
    const float* inw  = in_proj_w + (size_t)i*256*64;
    const float* cw   = conv_w    + (size_t)i*128*4;
    const float* cb   = conv_b    + (size_t)i*128;
    const float* xpw  = x_proj_w  + (size_t)i*36*128;
    const float* dtw  = dt_w      + (size_t)i*128*4;
    const float* dtb  = dt_b      + (size_t)i*128;
    const float* alog = A_log     + (size_t)i*128*16;
    const float* dp   = Dp        + (size_t)i*128;
    const float* opw  = out_proj_w+ (size_t)i*64*128;
    const float* w1   = mlp_w1    + (size_t)i*256*64;
    const float* b1   = mlp_b1    + (size_t)i*256;
    const float* w2   = mlp_w2    + (size_t)i*64*256;
    const float* b2   = mlp_b2    + (size_t)i*64;

    k_ln_gemm<0><<<TTOK/16,256,0,stream>>>(bufH, ln1_g+i*64, ln1_b+i*64, inw, nullptr, bufXZ, 16);
    k_dwconv<<<gD,256,0,stream>>>(bufXZ, cw, cb, bufXC);
    k_xproj_delta<<<(TTOK+111)/112,256,0,stream>>>(bufXC, xpw, dtw, dtb, bufDBL, bufDLT, 112);
    k_scan1<<<BSZ*NCH*2048/256,256,0,stream>>>(bufDLT, bufXC, bufDBL, alog, chA, chH);
    k_scan2<<<(BSZ*2048+255)/256,256,0,stream>>>(chA, chH, chIn);
    k_scan3<<<BSZ*NCH*128/16,256,0,stream>>>(bufDLT, bufXC, bufDBL, alog, chIn, bufXZ, dp, bufY);
    gemm_launch(bufY, opw, nullptr, bufH, bufH, TTOK, 64, 128, 2, stream);
    k_ln_gemm<1><<<TTOK/16,256,0,stream>>>(bufH, ln2_g+i*64, ln2_b+i*64, w1, b1, bufXZ, 16);
    gemm_launch(bufXZ, w2, b2, bufH, bufH, TTOK, 64, 256, 2, stream);
  }

  k_pool1<<<256,256,0,stream>>>(bufH, partial);
  k_pool2<<<1,128,0,stream>>>(partial, fc_w, fc_b, (float*)d_out);
}